// Round 3
// baseline (449.027 us; speedup 1.0000x reference)
//
#include <hip/hip_runtime.h>
#include <math.h>

#define D_MODEL 1024
#define NHEAD   16
#define HDIM    64
#define SEQ     2048
#define BATCH   2
#define NROWS   (BATCH*SEQ)   // 4096

typedef unsigned short u16;
typedef __attribute__((ext_vector_type(8))) short short8;
typedef __attribute__((ext_vector_type(4))) float f32x4;

// ---- bf16 helpers ----
__device__ __forceinline__ u16 f2bf(float x) {           // RNE
    unsigned int u = __float_as_uint(x);
    u += 0x7fffu + ((u >> 16) & 1u);
    return (u16)(u >> 16);
}
__device__ __forceinline__ u16 f2bf_trunc(float x) {     // truncate (1 op)
    return (u16)(__float_as_uint(x) >> 16);
}
__device__ __forceinline__ float bf2f(u16 h) {
    return __uint_as_float(((unsigned int)h) << 16);
}

// ---------------------------------------------------------------- gdiag
// gdiag[h,d] = (sum_i A[h,i,d]^2 + exp(log_lambda[h])) * log2(e)
__global__ void gdiag_kernel(const float* __restrict__ A,
                             const float* __restrict__ log_lambda,
                             float* __restrict__ gdiag) {
    int id = blockIdx.x * 256 + threadIdx.x;
    if (id >= NHEAD * HDIM) return;
    int h = id >> 6, d = id & 63;
    float s = 0.f;
#pragma unroll
    for (int i = 0; i < 16; ++i) {
        float a = A[(h * 16 + i) * HDIM + d];
        s += a * a;
    }
    gdiag[id] = (s + __expf(log_lambda[h])) * 1.4426950408889634f;
}

// ---------------------------------------------------------------- prep: fp32 -> bf16 hi/lo
__global__ void prep_split(const float* __restrict__ x,
                           const float* __restrict__ Wq, const float* __restrict__ Wk,
                           const float* __restrict__ Wv, const float* __restrict__ Wo,
                           u16* __restrict__ xh, u16* __restrict__ xl,
                           u16* __restrict__ wqh, u16* __restrict__ wql,
                           u16* __restrict__ wkh, u16* __restrict__ wkl,
                           u16* __restrict__ wvh, u16* __restrict__ woh) {
    int seg = blockIdx.y;
    int i = blockIdx.x * 256 + threadIdx.x;   // float4 index
    const float* src; u16* dh; u16* dl; int n4;
    if      (seg == 0) { src = x;  dh = xh;  dl = xl;      n4 = NROWS * D_MODEL / 4; }
    else if (seg == 1) { src = Wq; dh = wqh; dl = wql;     n4 = D_MODEL * D_MODEL / 4; }
    else if (seg == 2) { src = Wk; dh = wkh; dl = wkl;     n4 = D_MODEL * D_MODEL / 4; }
    else if (seg == 3) { src = Wv; dh = wvh; dl = nullptr; n4 = D_MODEL * D_MODEL / 4; }
    else               { src = Wo; dh = woh; dl = nullptr; n4 = D_MODEL * D_MODEL / 4; }
    if (i >= n4) return;
    float4 v = *(const float4*)&src[(size_t)i * 4];
    float vv[4] = {v.x, v.y, v.z, v.w};
    u16 hv[4], lv[4];
#pragma unroll
    for (int j = 0; j < 4; ++j) {
        u16 hb = f2bf(vv[j]);
        hv[j] = hb;
        lv[j] = f2bf(vv[j] - bf2f(hb));
    }
    *(uint2*)&dh[(size_t)i * 4] = *(uint2*)hv;
    if (dl) *(uint2*)&dl[(size_t)i * 4] = *(uint2*)lv;
}

// ---------------------------------------------------------------- MFMA NT GEMM
// out[r][c] = sum_k A[r][k]*W[c][k] + bias[c]; bf16 hi(/lo), fp32 acc.
// NP3: 3-pass split (ah*bh + ah*bl + al*bh); else 1-pass plain bf16.
// LDS rows padded to 40 u16 (80 B): 16B-aligned b128 frag access, <=2-way banks.
template<int NP3>
__global__ __launch_bounds__(256)
void gemm_mfma(const u16* __restrict__ Ah, const u16* __restrict__ Al,
               const u16* __restrict__ BhA, const u16* __restrict__ BlA, const float* __restrict__ biasA,
               float* outfA, u16* auxhA, u16* auxlA, float* ksumA,
               const u16* __restrict__ BhB, const u16* __restrict__ BlB, const float* __restrict__ biasB,
               float* outfB, u16* auxhB, u16* auxlB, float* ksumB,
               int out_layout) {
    const int z = blockIdx.z;
    const u16* Bh = (z == 0) ? BhA : BhB;
    const u16* Bl = (z == 0) ? BlA : BlB;
    const float* bias = (z == 0) ? biasA : biasB;
    float* outf = (z == 0) ? outfA : outfB;
    u16* auxh   = (z == 0) ? auxhA : auxhB;
    u16* auxl   = (z == 0) ? auxlA : auxlB;
    float* ksump= (z == 0) ? ksumA : ksumB;

    __shared__ __align__(16) u16 As_h[128][40], Bs_h[128][40];
    __shared__ __align__(16) u16 As_l[NP3 ? 128 : 1][40], Bs_l[NP3 ? 128 : 1][40];

    const int tid = threadIdx.x;
    const int w = tid >> 6, lane = tid & 63, quad = lane >> 4, n16 = lane & 15;
    const int rBase = blockIdx.y * 128;
    const int cBase = blockIdx.x * 128;

    f32x4 acc[2][8] = {};

    for (int kt = 0; kt < D_MODEL; kt += 32) {
#pragma unroll
        for (int s = 0; s < 2; ++s) {
            int id = s * 256 + tid;          // 512 chunks of 8 bf16
            int row = id >> 2;
            int c8 = (id & 3) * 8;
            *(short8*)&As_h[row][c8] = *(const short8*)&Ah[(size_t)(rBase + row) * D_MODEL + kt + c8];
            *(short8*)&Bs_h[row][c8] = *(const short8*)&Bh[(size_t)(cBase + row) * D_MODEL + kt + c8];
            if (NP3) {
                *(short8*)&As_l[row][c8] = *(const short8*)&Al[(size_t)(rBase + row) * D_MODEL + kt + c8];
                *(short8*)&Bs_l[row][c8] = *(const short8*)&Bl[(size_t)(cBase + row) * D_MODEL + kt + c8];
            }
        }
        __syncthreads();

        short8 a_h[2], a_l[2];
#pragma unroll
        for (int mt = 0; mt < 2; ++mt) {
            a_h[mt] = *(const short8*)&As_h[w * 32 + mt * 16 + n16][quad * 8];
            if (NP3) a_l[mt] = *(const short8*)&As_l[w * 32 + mt * 16 + n16][quad * 8];
        }
#pragma unroll
        for (int nt = 0; nt < 8; ++nt) {
            short8 b_h = *(const short8*)&Bs_h[nt * 16 + n16][quad * 8];
            short8 b_l;
            if (NP3) b_l = *(const short8*)&Bs_l[nt * 16 + n16][quad * 8];
#pragma unroll
            for (int mt = 0; mt < 2; ++mt) {
                acc[mt][nt] = __builtin_amdgcn_mfma_f32_16x16x32_bf16(a_h[mt], b_h, acc[mt][nt], 0, 0, 0);
                if (NP3) {
                    acc[mt][nt] = __builtin_amdgcn_mfma_f32_16x16x32_bf16(a_h[mt], b_l, acc[mt][nt], 0, 0, 0);
                    acc[mt][nt] = __builtin_amdgcn_mfma_f32_16x16x32_bf16(a_l[mt], b_h, acc[mt][nt], 0, 0, 0);
                }
            }
        }
        __syncthreads();
    }

    // epilogue: C row = quad*4+reg (within 16x16 tile), col = n16
    float csum[8];
#pragma unroll
    for (int nt = 0; nt < 8; ++nt) csum[nt] = 0.f;
#pragma unroll
    for (int mt = 0; mt < 2; ++mt) {
#pragma unroll
        for (int nt = 0; nt < 8; ++nt) {
            int c = cBase + nt * 16 + n16;
            float bc = bias[c];
            int rb = rBase + w * 32 + mt * 16 + quad * 4;
#pragma unroll
            for (int reg = 0; reg < 4; ++reg) {
                float val = acc[mt][nt][reg] + bc;
                int rr = rb + reg;
                size_t idx = out_layout
                    ? ((size_t)(((rr >> 11) * NHEAD + (c >> 6)) * SEQ + (rr & (SEQ - 1)))) * HDIM + (c & 63)
                    : (size_t)rr * D_MODEL + c;
                if (outf) outf[idx] = val;
                if (auxh) {
                    u16 hb = f2bf(val);
                    auxh[idx] = hb;
                    if (auxl) auxl[idx] = f2bf(val - bf2f(hb));
                }
                csum[nt] += val;
            }
        }
    }
    if (ksump) {
#pragma unroll
        for (int nt = 0; nt < 8; ++nt) {
            float cs = csum[nt];
            cs += __shfl_xor(cs, 16);
            cs += __shfl_xor(cs, 32);
            if (quad == 0) {
                int c = cBase + nt * 16 + n16;
                int bb = rBase >> 11;
                atomicAdd(&ksump[(bb * NHEAD + (c >> 6)) * HDIM + (c & 63)], cs);
            }
        }
    }
}

// ---------------------------------------------------------------- v transpose: (b,h,t,hd) bf16 -> (b,h,hd,t)
__global__ __launch_bounds__(256)
void vtrans_kernel(const u16* __restrict__ vh, u16* __restrict__ vT) {
    __shared__ __align__(16) u16 tile[64][72];
    const int tid = threadIdx.x;
    const int t0 = blockIdx.x * 64;
    const int bh = blockIdx.y;
    const u16* vp = vh + (size_t)bh * SEQ * HDIM;
#pragma unroll
    for (int s = 0; s < 2; ++s) {
        int id = s * 256 + tid;
        int row = id >> 3, c8 = (id & 7) * 8;
        *(short8*)&tile[row][c8] = *(const short8*)&vp[(size_t)(t0 + row) * HDIM + c8];
    }
    __syncthreads();
#pragma unroll
    for (int s = 0; s < 2; ++s) {
        int id = s * 256 + tid;
        int d = id >> 3, t8 = (id & 7) * 8;
        short8 r;
#pragma unroll
        for (int i = 0; i < 8; ++i) r[i] = (short)tile[t8 + i][d];
        *(short8*)&vT[((size_t)bh * HDIM + d) * SEQ + t0 + t8] = r;
    }
}

// ---------------------------------------------------------------- flash attention v3
// j-split across waves: wave w owns j-strips {it*128 + w*32}. All waves cover the
// same 64 q-rows (Sg hi/lo in registers). K/V fragments load global->register
// (16B contiguous per lane). LDS: only P round-trip per wave + final merge.
// No __syncthreads in the main loop.
__global__ __launch_bounds__(256, 2)
void flash_v3(const float* __restrict__ q, const u16* __restrict__ kh,
              const u16* __restrict__ kl, const u16* __restrict__ vT,
              const float* __restrict__ ksum, const float* __restrict__ gdiag,
              u16* __restrict__ o) {
    __shared__ __align__(16) char smem_raw[4 * 64 * 40 * 2];   // ps[4][64][40] u16 / Osum[64][68] f32
    __shared__ float mls[4][2][64];
    __shared__ float ltot_lds[64];

    const int tid = threadIdx.x;
    const int w = tid >> 6, lane = tid & 63, quad = lane >> 4, n16 = lane & 15;
    const int t0 = blockIdx.x * 64;
    const int h = blockIdx.y, b = blockIdx.z;
    const size_t bh = (size_t)b * NHEAD + h;
    const float* qp = q + bh * SEQ * HDIM;
    const u16* khp = kh + bh * SEQ * HDIM;
    const u16* klp = kl + bh * SEQ * HDIM;
    const u16* vtp = vT + bh * HDIM * SEQ;
    u16* psw = (u16*)smem_raw + w * 64 * 40;

    // ---- Sg A-fragments (hi/lo) in registers: all 64 rows, all 64 dims ----
    // A[m = mt*16+n16][k = kc*32 + quad*8 + j]
    short8 sgh[4][2], sgl[4][2];
#pragma unroll
    for (int mt = 0; mt < 4; ++mt) {
#pragma unroll
        for (int kc = 0; kc < 2; ++kc) {
            int row = t0 + mt * 16 + n16;
            int d0 = kc * 32 + quad * 8;
            float4 q0 = *(const float4*)&qp[(size_t)row * HDIM + d0];
            float4 q1 = *(const float4*)&qp[(size_t)row * HDIM + d0 + 4];
            float4 k0 = *(const float4*)&ksum[bh * HDIM + d0];
            float4 k1 = *(const float4*)&ksum[bh * HDIM + d0 + 4];
            float4 g0 = *(const float4*)&gdiag[(size_t)h * HDIM + d0];
            float4 g1 = *(const float4*)&gdiag[(size_t)h * HDIM + d0 + 4];
            float sg[8];
            sg[0] = (2048.f * q0.x - k0.x) * g0.x; sg[1] = (2048.f * q0.y - k0.y) * g0.y;
            sg[2] = (2048.f * q0.z - k0.z) * g0.z; sg[3] = (2048.f * q0.w - k0.w) * g0.w;
            sg[4] = (2048.f * q1.x - k1.x) * g1.x; sg[5] = (2048.f * q1.y - k1.y) * g1.y;
            sg[6] = (2048.f * q1.z - k1.z) * g1.z; sg[7] = (2048.f * q1.w - k1.w) * g1.w;
#pragma unroll
            for (int j = 0; j < 8; ++j) {
                u16 hb = f2bf(sg[j]);
                sgh[mt][kc][j] = (short)hb;
                sgl[mt][kc][j] = (short)f2bf(sg[j] - bf2f(hb));
            }
        }
    }

    f32x4 oacc[4][4] = {};       // [mt][ntd]
    float m_i[16], l_i[16];
#pragma unroll
    for (int i = 0; i < 16; ++i) { m_i[i] = -INFINITY; l_i[i] = 0.f; }

    short8 ones;
#pragma unroll
    for (int j = 0; j < 8; ++j) ones[j] = (short)0x3F80;   // bf16 1.0

    for (int it = 0; it < SEQ / 128; ++it) {
        const int jw = it * 128 + w * 32;

        // ---- B-fragments direct global->register ----
        short8 bkh[2][2], bkl[2][2];   // [kc][ntj]: B[k=d][n=t]
#pragma unroll
        for (int kc = 0; kc < 2; ++kc)
#pragma unroll
            for (int ntj = 0; ntj < 2; ++ntj) {
                size_t off = (size_t)(jw + ntj * 16 + n16) * HDIM + kc * 32 + quad * 8;
                bkh[kc][ntj] = *(const short8*)&khp[off];
                bkl[kc][ntj] = *(const short8*)&klp[off];
            }
        short8 bv[4];                  // [ntd]: B[k=j][n=d] from vT[d][t]
#pragma unroll
        for (int ntd = 0; ntd < 4; ++ntd)
            bv[ntd] = *(const short8*)&vtp[(size_t)(ntd * 16 + n16) * SEQ + jw + quad * 8];

        // ---- QK^T, 3-pass split-bf16: lg[ntj][mt], rows quad*4+r, col n16 ----
        f32x4 lg[2][4] = {};
#pragma unroll
        for (int kc = 0; kc < 2; ++kc)
#pragma unroll
            for (int ntj = 0; ntj < 2; ++ntj)
#pragma unroll
                for (int mt = 0; mt < 4; ++mt) {
                    lg[ntj][mt] = __builtin_amdgcn_mfma_f32_16x16x32_bf16(sgh[mt][kc], bkh[kc][ntj], lg[ntj][mt], 0, 0, 0);
                    lg[ntj][mt] = __builtin_amdgcn_mfma_f32_16x16x32_bf16(sgh[mt][kc], bkl[kc][ntj], lg[ntj][mt], 0, 0, 0);
                    lg[ntj][mt] = __builtin_amdgcn_mfma_f32_16x16x32_bf16(sgl[mt][kc], bkh[kc][ntj], lg[ntj][mt], 0, 0, 0);
                }

        // ---- online softmax (log2 domain) ----
#pragma unroll
        for (int mt = 0; mt < 4; ++mt)
#pragma unroll
            for (int r = 0; r < 4; ++r) {
                int idx = mt * 4 + r;
                float mx = fmaxf(lg[0][mt][r], lg[1][mt][r]);
                mx = fmaxf(mx, __shfl_xor(mx, 1));
                mx = fmaxf(mx, __shfl_xor(mx, 2));
                mx = fmaxf(mx, __shfl_xor(mx, 4));
                mx = fmaxf(mx, __shfl_xor(mx, 8));
                float mn = fmaxf(m_i[idx], mx);
                float alpha = exp2f(m_i[idx] - mn);
                m_i[idx] = mn;
                float p0 = exp2f(lg[0][mt][r] - mn);
                float p1 = exp2f(lg[1][mt][r] - mn);
                int m = mt * 16 + quad * 4 + r;
                psw[m * 40 + n16]      = f2bf_trunc(p0);
                psw[m * 40 + 16 + n16] = f2bf_trunc(p1);
                l_i[idx] *= alpha;
#pragma unroll
                for (int ntd = 0; ntd < 4; ++ntd) oacc[mt][ntd][r] *= alpha;
            }

        // ---- PV + row-sum via ones-MFMA (same-wave DS is in-order: no barrier) ----
#pragma unroll
        for (int mt = 0; mt < 4; ++mt) {
            short8 pa = *(const short8*)&psw[(mt * 16 + n16) * 40 + quad * 8];
            f32x4 ls = {};
            ls = __builtin_amdgcn_mfma_f32_16x16x32_bf16(pa, ones, ls, 0, 0, 0);
#pragma unroll
            for (int r = 0; r < 4; ++r) l_i[mt * 4 + r] += ls[r];
#pragma unroll
            for (int ntd = 0; ntd < 4; ++ntd)
                oacc[mt][ntd] = __builtin_amdgcn_mfma_f32_16x16x32_bf16(pa, bv[ntd], oacc[mt][ntd], 0, 0, 0);
        }
    }

    // ---- merge the 4 waves' (m, l, O) ----
#pragma unroll
    for (int mt = 0; mt < 4; ++mt)
#pragma unroll
        for (int r = 0; r < 4; ++r)
            if (n16 == 0) {
                int m = mt * 16 + quad * 4 + r;
                mls[w][0][m] = m_i[mt * 4 + r];
                mls[w][1][m] = l_i[mt * 4 + r];
            }
    __syncthreads();   // mls ready; also last ps reads done before Osum aliases

    float scale_own[16];
#pragma unroll
    for (int mt = 0; mt < 4; ++mt)
#pragma unroll
        for (int r = 0; r < 4; ++r) {
            int idx = mt * 4 + r;
            int m = mt * 16 + quad * 4 + r;
            float M = fmaxf(fmaxf(mls[0][0][m], mls[1][0][m]), fmaxf(mls[2][0][m], mls[3][0][m]));
            float lt = exp2f(mls[0][0][m] - M) * mls[0][1][m]
                     + exp2f(mls[1][0][m] - M) * mls[1][1][m]
                     + exp2f(mls[2][0][m] - M) * mls[2][1][m]
                     + exp2f(mls[3][0][m] - M) * mls[3][1][m];
            scale_own[idx] = exp2f(m_i[idx] - M);
            if (w == 0 && n16 == 0) ltot_lds[m] = lt;
        }

    float* Os = (float*)smem_raw;   // [64][68]
#pragma unroll
    for (int ww = 0; ww < 4; ++ww) {
        if (w == ww) {
#pragma unroll
            for (int mt = 0; mt < 4; ++mt)
#pragma unroll
                for (int ntd = 0; ntd < 4; ++ntd)
#pragma unroll
                    for (int r = 0; r < 4; ++r) {
                        int m = mt * 16 + quad * 4 + r;
                        int c = ntd * 16 + n16;
                        float val = oacc[mt][ntd][r] * scale_own[mt * 4 + r];
                        if (ww == 0) Os[m * 68 + c] = val;
                        else         Os[m * 68 + c] += val;
                    }
        }
        __syncthreads();
    }

    // ---- normalize + write bf16 (b, t, h*64+d) ----
    {
        int orow = tid >> 2;
        int c0 = (tid & 3) * 16;
        float inv = 1.f / ltot_lds[orow];
        u16 outv[16];
#pragma unroll
        for (int cc = 0; cc < 16; ++cc)
            outv[cc] = f2bf(Os[orow * 68 + c0 + cc] * inv);
        u16* dst = o + ((size_t)(b * SEQ + t0 + orow)) * D_MODEL + h * HDIM + c0;
        *(uint4*)dst = *(uint4*)outv;
        *(uint4*)(dst + 8) = *(uint4*)(outv + 8);
    }
}

// ---------------------------------------------------------------- launcher
extern "C" void kernel_launch(void* const* d_in, const int* in_sizes, int n_in,
                              void* d_out, int out_size, void* d_ws, size_t ws_size,
                              hipStream_t stream) {
    const float* x  = (const float*)d_in[0];
    const float* Wq = (const float*)d_in[1];
    const float* bq = (const float*)d_in[2];
    const float* Wk = (const float*)d_in[3];
    const float* bk = (const float*)d_in[4];
    const float* Wv = (const float*)d_in[5];
    const float* bv = (const float*)d_in[6];
    const float* Wo = (const float*)d_in[7];
    const float* bo = (const float*)d_in[8];
    const float* A  = (const float*)d_in[9];
    const float* ll = (const float*)d_in[10];
    float* out = (float*)d_out;

    const size_t NQKV = (size_t)NROWS * D_MODEL;   // 4,194,304
    const size_t NW = (size_t)D_MODEL * D_MODEL;   // 1,048,576
    char* base = (char*)d_ws;
    float* q_ws = (float*)base;            base += NQKV * 4;
    u16* xh  = (u16*)base;                 base += NQKV * 2;   // reused as o_hi after QKV
    u16* xl  = (u16*)base;                 base += NQKV * 2;   // reused as vT after QKV
    u16* khw = (u16*)base;                 base += NQKV * 2;
    u16* klw = (u16*)base;                 base += NQKV * 2;
    u16* vhw = (u16*)base;                 base += NQKV * 2;
    u16* wqh = (u16*)base;                 base += NW * 2;
    u16* wql = (u16*)base;                 base += NW * 2;
    u16* wkh = (u16*)base;                 base += NW * 2;
    u16* wkl = (u16*)base;                 base += NW * 2;
    u16* wvh = (u16*)base;                 base += NW * 2;
    u16* woh = (u16*)base;                 base += NW * 2;
    float* gd_ws   = (float*)base;         base += NHEAD * HDIM * 4;
    float* ksum_ws = (float*)base;         base += BATCH * NHEAD * HDIM * 4;

    hipMemsetAsync(ksum_ws, 0, BATCH * NHEAD * HDIM * sizeof(float), stream);

    prep_split<<<dim3(4096, 5), 256, 0, stream>>>(x, Wq, Wk, Wv, Wo,
                                                  xh, xl, wqh, wql, wkh, wkl, wvh, woh);
    gdiag_kernel<<<4, 256, 0, stream>>>(A, ll, gd_ws);

    // Q (z=0) + K (z=1): 3-pass split-bf16; K writes k_hi/k_lo + ksum atomics
    gemm_mfma<1><<<dim3(8, 32, 2), 256, 0, stream>>>(
        xh, xl,
        wqh, wql, bq, q_ws, nullptr, nullptr, nullptr,
        wkh, wkl, bk, nullptr, khw, klw, ksum_ws,
        1);
    // V: 1-pass bf16
    gemm_mfma<0><<<dim3(8, 32, 1), 256, 0, stream>>>(
        xh, nullptr,
        wvh, nullptr, bv, nullptr, vhw, nullptr, nullptr,
        wvh, nullptr, bv, nullptr, vhw, nullptr, nullptr,
        1);

    u16* vTw = xl;   // alias: x_lo dead after QKV GEMMs
    u16* ohw = xh;   // alias: x_hi dead after QKV GEMMs
    vtrans_kernel<<<dim3(SEQ / 64, BATCH * NHEAD), 256, 0, stream>>>(vhw, vTw);

    flash_v3<<<dim3(SEQ / 64, NHEAD, BATCH), 256, 0, stream>>>(
        q_ws, khw, klw, vTw, ksum_ws, gd_ws, ohw);

    // out-proj: 1-pass bf16, row-major fp32 output
    gemm_mfma<0><<<dim3(8, 32, 1), 256, 0, stream>>>(
        ohw, nullptr,
        woh, nullptr, bo, out, nullptr, nullptr, nullptr,
        woh, nullptr, bo, out, nullptr, nullptr, nullptr,
        0);
}